// Round 3
// 116.590 us; speedup vs baseline: 1.0582x; 1.0582x over previous
//
#include <hip/hip_runtime.h>
#include <hip/hip_bf16.h>

#define ATTN_N 8192
#define ATTN_D 128
#define TKEYS 64                      // keys per LDS tile (was 128)
#define NTILES (ATTN_N / TKEYS)       // 128
#define TILE_ELEMS (TKEYS * ATTN_D)   // 8192 bf16 = 16 KB
#define QROWS 64                      // queries per block
#define SPLITK 4                      // 4-way split-K -> 512 blocks = 2/CU
#define KTPB (NTILES / SPLITK)        // 32 key tiles per block

typedef __bf16 bf16_t;
typedef bf16_t bf16x2 __attribute__((ext_vector_type(2)));
typedef bf16_t bf16x8 __attribute__((ext_vector_type(8)));
typedef float f32x4 __attribute__((ext_vector_type(4)));

#if __has_builtin(__builtin_amdgcn_exp2f)
#define EXP2(x) __builtin_amdgcn_exp2f(x)
#else
#define EXP2(x) __expf((x) * 0.6931471805599453f)
#endif

// Async global->LDS DMA, 16 B per lane; lane-linear on both sides (m104).
__device__ __forceinline__ void dma16(const bf16_t* g, bf16_t* l) {
  __builtin_amdgcn_global_load_lds(
      (const __attribute__((address_space(1))) void*)g,
      (__attribute__((address_space(3))) void*)l, 16, 0, 0);
}

// ---------------------------------------------------------------------------
// Prep: Q -> bf16 linear (scaled by log2(e)/sqrt(128), so flash uses exp2);
//       K -> bf16 key-linear image kswz (16B chunk j stored at j ^ (key&15));
//       V -> bf16 transposed 64-key tile image vtswz: tile kt64 = key/64 is
//            [d=0..127][key=0..63]; key positions pairwise interleaved per
//            32-key window (chunk j = kq*4+quad holds keys 32kq+4quad+
//            (i>>1)+16(i&1)); 16B chunks XOR'd by d&7.
//   grid (N/64, 2) x 256 threads.
// ---------------------------------------------------------------------------
__global__ void prep_kernel(const float* __restrict__ q,
                            const float* __restrict__ k,
                            const float* __restrict__ v,
                            bf16_t* __restrict__ qb,
                            bf16_t* __restrict__ kswz,
                            bf16_t* __restrict__ vtswz) {
  __shared__ bf16_t tile[64][72];
  const int bk = blockIdx.x;      // 64-key block == V tile index, 0..127
  const int bd = blockIdx.y;      // 64-d half, 0..1
  const int t = threadIdx.x;      // 0..255
  const float sc = 0.12751744f;   // log2(e) / sqrt(128)

  const int row_l = t >> 2;             // 0..63
  const int key = bk * 64 + row_l;

#pragma unroll
  for (int u = 0; u < 2; ++u) {
    const int j = bd * 8 + (t & 3) * 2 + u;   // d-chunk 0..15
    const float4* qs = (const float4*)(q + (size_t)key * ATTN_D + j * 8);
    const float4* ks = (const float4*)(k + (size_t)key * ATTN_D + j * 8);
    float4 a0 = qs[0], a1 = qs[1];
    float4 b0 = ks[0], b1 = ks[1];
    bf16x8 qo, ko;
    qo[0] = (bf16_t)(a0.x * sc); qo[1] = (bf16_t)(a0.y * sc);
    qo[2] = (bf16_t)(a0.z * sc); qo[3] = (bf16_t)(a0.w * sc);
    qo[4] = (bf16_t)(a1.x * sc); qo[5] = (bf16_t)(a1.y * sc);
    qo[6] = (bf16_t)(a1.z * sc); qo[7] = (bf16_t)(a1.w * sc);
    ko[0] = (bf16_t)b0.x; ko[1] = (bf16_t)b0.y;
    ko[2] = (bf16_t)b0.z; ko[3] = (bf16_t)b0.w;
    ko[4] = (bf16_t)b1.x; ko[5] = (bf16_t)b1.y;
    ko[6] = (bf16_t)b1.z; ko[7] = (bf16_t)b1.w;
    *(bf16x8*)(qb + (size_t)key * ATTN_D + j * 8) = qo;
    *(bf16x8*)(kswz + (size_t)key * ATTN_D + ((j ^ (key & 15)) * 8)) = ko;
  }

  {
    const float* src = v + (size_t)key * ATTN_D + bd * 64 + (t & 3) * 16;
#pragma unroll
    for (int u = 0; u < 4; ++u) {
      float4 a = ((const float4*)src)[u];
      tile[row_l][(t & 3) * 16 + u * 4 + 0] = (bf16_t)a.x;
      tile[row_l][(t & 3) * 16 + u * 4 + 1] = (bf16_t)a.y;
      tile[row_l][(t & 3) * 16 + u * 4 + 2] = (bf16_t)a.z;
      tile[row_l][(t & 3) * 16 + u * 4 + 3] = (bf16_t)a.w;
    }
  }
  __syncthreads();
  {
    const int d_l = t >> 2;            // 0..63
    const int d = bd * 64 + d_l;
#pragma unroll
    for (int u = 0; u < 2; ++u) {
      const int j = (t & 3) * 2 + u;   // key-chunk position 0..7
      bf16x8 o;
#pragma unroll
      for (int i = 0; i < 8; ++i) {
        const int kl_ = 32 * (j >> 2) + 4 * (j & 3) + (i >> 1) + 16 * (i & 1);
        o[i] = tile[kl_][d_l];
      }
      *(bf16x8*)(vtswz + (size_t)bk * TILE_ELEMS + d * TKEYS +
                 ((j ^ (d & 7)) * 8)) = o;
    }
  }
}

// ---------------------------------------------------------------------------
// Flash attention, 64 queries/block x 4-way split-K.
//   grid = 512 blocks x 512 threads (8 waves), LDS 74.5 KB -> 2 blocks/CU,
//   4 waves/SIMD (was 1 block/CU, 2 waves/SIMD). Two independent barrier
//   groups per CU: while one block drains its DMA barrier, the other's
//   waves keep the MFMA pipe fed (m114 wave-level overlap).
//   Block b: query group b>>2 (rows 64*(b>>2)..+63), key quarter b&3
//   (tiles kh*32..+31 of 64-key tiles).
//   Wave w: rowQ = w&3 (16-row m-subtile), keyQ = w>>2 (32-key window).
//   Per wave-iter: 8 QK-MFMA + 8 PV-MFMA. exp2-only softmax (pure-sum
//   denominator), DMA double-buffer, one barrier/iter, s_setprio(1) around
//   MFMA clusters (T5). Writes UNNORMALIZED partial O + partial L; merge
//   kernel sums the 4 split-K partials and normalizes.
//   XCD residency: blockIdx%8 = XCD; kh = b&3 is constant per XCD, so each
//   XCD's L2 holds one 1 MB key-quarter. Co-resident blocks (b, b+256)
//   share kh AND tile stagger -> their DMAs hit the same L2 lines.
// MFMA layouts (mfma_f32_16x16x32_bf16, verified gfx950):
//   A: m = lane&15, k = (lane>>4)*8 + j
//   B: n = lane&15, k = (lane>>4)*8 + j
//   C/D: col = lane&15, row = (lane>>4)*4 + reg
// ---------------------------------------------------------------------------
__global__ __launch_bounds__(512, 4) void flash_attn_kernel(
    const bf16_t* __restrict__ qb, const bf16_t* __restrict__ kswz,
    const bf16_t* __restrict__ vtswz, float* __restrict__ partO,
    float* __restrict__ partL) {
  __shared__ __align__(16) bf16_t KV[2][2][TILE_ELEMS];  // 64 KB
  __shared__ __align__(16) bf16_t Ps[8][16][40];         // 10 KB
  __shared__ float cmb[8][16];                           // 512 B
  // Epilogue-only merge buffer aliased over the (dead) KV storage.
  float* Ob = (float*)&KV[0][0][0];                      // [64][132] stride pad

  const int t = threadIdx.x;
  const int w = t >> 6;
  const int lane = t & 63;
  const int quad = lane >> 4;
  const int col = lane & 15;
  const int rowQ = w & 3;
  const int keyQ = w >> 2;
  const int blk = blockIdx.x;
  const int qg = blk >> 2;
  const int kh = blk & 3;
  const int q0 = qg * QROWS;
  const int ktbase = kh * KTPB;
  const int stg = ((blk >> 3) & 3) * 8;   // first-pass L3 decorrelation

  // Swizzled LDS offsets (row*stride + (chunk^swz)*8).
  int offK[4][2], offV[8];
#pragma unroll
  for (int c = 0; c < 4; ++c)
#pragma unroll
    for (int ni = 0; ni < 2; ++ni)
      offK[c][ni] = (keyQ * 32 + ni * 16 + col) * ATTN_D +
                    (((c * 4 + quad) ^ col) * 8);
#pragma unroll
  for (int ds = 0; ds < 8; ++ds)
    offV[ds] = (ds * 16 + col) * TKEYS + (((keyQ * 4 + quad) ^ (col & 7)) * 8);

  // Q fragments: one 16-row subtile x 4 k-chunks, registers for whole kernel.
  bf16x8 aq[4];
  {
    const int row = q0 + rowQ * 16 + col;
#pragma unroll
    for (int c = 0; c < 4; ++c)
      aq[c] = *(const bf16x8*)(qb + (size_t)row * ATTN_D + c * 32 + quad * 8);
  }

  f32x4 oacc[8];
#pragma unroll
  for (int i = 0; i < 8; ++i) oacc[i] = (f32x4){0.f, 0.f, 0.f, 0.f};
  float l_part[4] = {0.f, 0.f, 0.f, 0.f};

  // Prologue DMA: first tile pair into buf 0 (2x 16 KB, 2 dma16 each).
  {
    const int kt = ktbase + (stg & (KTPB - 1));
    const bf16_t* kg = kswz + (size_t)kt * TILE_ELEMS + t * 8;
    const bf16_t* vg = vtswz + (size_t)kt * TILE_ELEMS + t * 8;
#pragma unroll
    for (int u = 0; u < 2; ++u) {
      dma16(kg + u * 4096, &KV[0][0][t * 8 + u * 4096]);
      dma16(vg + u * 4096, &KV[0][1][t * 8 + u * 4096]);
    }
  }
  __syncthreads();

  for (int it = 0; it < KTPB; ++it) {
    const int buf = it & 1;
    if (it + 1 < KTPB) {
      const int nt = ktbase + ((stg + it + 1) & (KTPB - 1));
      const bf16_t* kg = kswz + (size_t)nt * TILE_ELEMS + t * 8;
      const bf16_t* vg = vtswz + (size_t)nt * TILE_ELEMS + t * 8;
      bf16_t* kl = &KV[buf ^ 1][0][t * 8];
      bf16_t* vl = &KV[buf ^ 1][1][t * 8];
#pragma unroll
      for (int u = 0; u < 2; ++u) {
        dma16(kg + u * 4096, kl + u * 4096);
        dma16(vg + u * 4096, vl + u * 4096);
      }
    }
    const bf16_t* Kb = KV[buf][0];
    const bf16_t* Vb = KV[buf][1];

    // --- S = Q K^T over this wave's 32-key window (2 n-subtiles).
    f32x4 s0 = (f32x4){0.f, 0.f, 0.f, 0.f};
    f32x4 s1 = (f32x4){0.f, 0.f, 0.f, 0.f};
    __builtin_amdgcn_s_setprio(1);
#pragma unroll
    for (int c = 0; c < 4; ++c) {
      bf16x8 b0 = *(const bf16x8*)(Kb + offK[c][0]);
      bf16x8 b1 = *(const bf16x8*)(Kb + offK[c][1]);
      s0 = __builtin_amdgcn_mfma_f32_16x16x32_bf16(aq[c], b0, s0, 0, 0, 0);
      s1 = __builtin_amdgcn_mfma_f32_16x16x32_bf16(aq[c], b1, s1, 0, 0, 0);
    }
    __builtin_amdgcn_s_setprio(0);

    // --- p = 2^s; lane-local denominator; packed pair-store (key i <-> pos
    //     2i, key i+16 <-> pos 2i+1 inside this wave's 32-key window).
#pragma unroll
    for (int r = 0; r < 4; ++r) {
      float p0 = EXP2(s0[r]);
      float p1 = EXP2(s1[r]);
      l_part[r] += p0 + p1;
      *(bf16x2*)&Ps[w][quad * 4 + r][col * 2] = (bf16x2){(bf16_t)p0, (bf16_t)p1};
    }

    // --- O += P V (K-dim = this wave's 32 keys, permuted order matches V img).
    bf16x8 ap = *(const bf16x8*)&Ps[w][col][quad * 8];
    __builtin_amdgcn_s_setprio(1);
#pragma unroll
    for (int ds = 0; ds < 8; ++ds) {
      bf16x8 bv = *(const bf16x8*)(Vb + offV[ds]);
      oacc[ds] = __builtin_amdgcn_mfma_f32_16x16x32_bf16(ap, bv, oacc[ds], 0, 0, 0);
    }
    __builtin_amdgcn_s_setprio(0);
    __syncthreads();  // drains prefetch vmcnt + protects buffer swap
  }

  // --- epilogue: denominator partials -> cmb; partial L to global.
#pragma unroll
  for (int r = 0; r < 4; ++r) {
    float v = l_part[r];
#pragma unroll
    for (int off = 1; off < 16; off <<= 1)
      v += __shfl_xor(v, off, 64);
    if (col == 0) cmb[w][quad * 4 + r] = v;
  }
  __syncthreads();
  if (t < QROWS) {
    const int rq = t >> 4, rl = t & 15;
    partL[(size_t)blk * QROWS + t] = cmb[rq][rl] + cmb[4 + rq][rl];
  }

  // --- 2-way keyQ merge of O into Ob (aliased on KV; stride 132).
#pragma unroll
  for (int p = 0; p < 2; ++p) {
    if (keyQ == p) {
#pragma unroll
      for (int ds = 0; ds < 8; ++ds)
#pragma unroll
        for (int r = 0; r < 4; ++r) {
          const int row = rowQ * 16 + quad * 4 + r;
          if (p == 0)
            Ob[row * 132 + ds * 16 + col] = oacc[ds][r];
          else
            Ob[row * 132 + ds * 16 + col] += oacc[ds][r];
        }
    }
    __syncthreads();
  }

  // --- cooperative write of the unnormalized 64x128 partial O.
  {
    float* dst = partO + (size_t)blk * (QROWS * ATTN_D);
    const int row = t >> 3;
    const int c0 = (t & 7) * 16;
#pragma unroll
    for (int u = 0; u < 4; ++u) {
      float4 vv = *(float4*)&Ob[row * 132 + c0 + u * 4];
      *(float4*)(dst + row * ATTN_D + c0 + u * 4) = vv;
    }
  }
}

// ---------------------------------------------------------------------------
// Merge: out[row] = (sum of 4 split-K partial O) / (sum of 4 partial L).
//   1024 blocks x 256 threads, one float4 per thread.
// ---------------------------------------------------------------------------
__global__ void merge_kernel(const float* __restrict__ partO,
                             const float* __restrict__ partL,
                             float* __restrict__ out) {
  const int idx = blockIdx.x * blockDim.x + threadIdx.x;  // float4 index
  const int row = idx >> 5;          // 32 float4 per 128-elem row
  const int gi = row >> 6;           // query group
  const int rl = row & 63;
  const int li = rl * 32 + (idx & 31);
  const float4* p0 = (const float4*)(partO + (size_t)(4 * gi + 0) * (QROWS * ATTN_D));
  const float4* p1 = (const float4*)(partO + (size_t)(4 * gi + 1) * (QROWS * ATTN_D));
  const float4* p2 = (const float4*)(partO + (size_t)(4 * gi + 2) * (QROWS * ATTN_D));
  const float4* p3 = (const float4*)(partO + (size_t)(4 * gi + 3) * (QROWS * ATTN_D));
  const float invL = 1.0f / (partL[(size_t)(4 * gi + 0) * QROWS + rl] +
                             partL[(size_t)(4 * gi + 1) * QROWS + rl] +
                             partL[(size_t)(4 * gi + 2) * QROWS + rl] +
                             partL[(size_t)(4 * gi + 3) * QROWS + rl]);
  float4 a = p0[li], b = p1[li], c = p2[li], d = p3[li], o;
  o.x = (a.x + b.x + c.x + d.x) * invL;
  o.y = (a.y + b.y + c.y + d.y) * invL;
  o.z = (a.z + b.z + c.z + d.z) * invL;
  o.w = (a.w + b.w + c.w + d.w) * invL;
  ((float4*)out)[idx] = o;
}

// ---------------------------------------------------------------------------
extern "C" void kernel_launch(void* const* d_in, const int* in_sizes, int n_in,
                              void* d_out, int out_size, void* d_ws, size_t ws_size,
                              hipStream_t stream) {
  const float* q = (const float*)d_in[0];
  const float* k = (const float*)d_in[1];
  const float* v = (const float*)d_in[2];
  float* out = (float*)d_out;

  // Workspace: qb | kswz | vtswz (bf16, 2 MB each) | partO 16.8 MB | partL 128 KB.
  bf16_t* qb = (bf16_t*)d_ws;
  bf16_t* kswz = qb + (size_t)ATTN_N * ATTN_D;
  bf16_t* vtswz = kswz + (size_t)ATTN_N * ATTN_D;
  float* partO = (float*)(vtswz + (size_t)ATTN_N * ATTN_D);
  float* partL = partO + (size_t)512 * QROWS * ATTN_D;

  prep_kernel<<<dim3(ATTN_N / 64, 2), 256, 0, stream>>>(q, k, v, qb, kswz, vtswz);
  flash_attn_kernel<<<512, 512, 0, stream>>>(qb, kswz, vtswz, partO, partL);
  merge_kernel<<<(ATTN_N * ATTN_D / 4) / 256, 256, 0, stream>>>(partO, partL, out);
}

// Round 4
// 109.338 us; speedup vs baseline: 1.1284x; 1.0663x over previous
//
#include <hip/hip_runtime.h>
#include <hip/hip_bf16.h>

#define ATTN_N 8192
#define ATTN_D 128
#define TKEYS 32                      // keys per LDS tile (was 64)
#define NTILES (ATTN_N / TKEYS)       // 256
#define TILE_ELEMS (TKEYS * ATTN_D)   // 4096 bf16 = 8 KB
#define QROWS 128                     // queries per block (8 waves x 16 rows)
#define SPLITK 8                      // 8-way split-K -> 512 blocks = 2/CU
#define KTPB (NTILES / SPLITK)        // 32 key tiles per block
#define NBUF 4                        // 4-deep LDS ring (T3/T4 counted vmcnt)

typedef __bf16 bf16_t;
typedef bf16_t bf16x2 __attribute__((ext_vector_type(2)));
typedef bf16_t bf16x8 __attribute__((ext_vector_type(8)));
typedef float f32x4 __attribute__((ext_vector_type(4)));

#if __has_builtin(__builtin_amdgcn_exp2f)
#define EXP2(x) __builtin_amdgcn_exp2f(x)
#else
#define EXP2(x) __expf((x) * 0.6931471805599453f)
#endif

// Async global->LDS DMA, 16 B per lane; lane-linear on both sides (m104).
__device__ __forceinline__ void dma16(const bf16_t* g, bf16_t* l) {
  __builtin_amdgcn_global_load_lds(
      (const __attribute__((address_space(1))) void*)g,
      (__attribute__((address_space(3))) void*)l, 16, 0, 0);
}

// ---------------------------------------------------------------------------
// Prep: Q -> bf16 linear (scaled by log2(e)/sqrt(128), so flash uses exp2);
//       K -> bf16 key-linear image kswz (16B chunk j stored at j ^ (key&15));
//       V -> bf16 transposed 32-key tile image vtswz: tile = key/32 is
//            [d=0..127][key=0..31]; chunk q (16B, 8 keys) holds keys
//            4q + (j>>1) + 16*(j&1) (pairwise interleave matching the packed
//            P layout); chunk slot XOR'd by (d>>1)&3 for bank spread.
//   grid (N/64, 2) x 256 threads.
// ---------------------------------------------------------------------------
__global__ void prep_kernel(const float* __restrict__ q,
                            const float* __restrict__ k,
                            const float* __restrict__ v,
                            bf16_t* __restrict__ qb,
                            bf16_t* __restrict__ kswz,
                            bf16_t* __restrict__ vtswz) {
  __shared__ bf16_t tile[64][72];
  const int bk = blockIdx.x;      // 64-key block -> two 32-key v-tiles
  const int bd = blockIdx.y;      // 64-d half, 0..1
  const int t = threadIdx.x;      // 0..255
  const float sc = 0.12751744f;   // log2(e) / sqrt(128)

  const int row_l = t >> 2;             // 0..63
  const int key = bk * 64 + row_l;

#pragma unroll
  for (int u = 0; u < 2; ++u) {
    const int j = bd * 8 + (t & 3) * 2 + u;   // d-chunk 0..15
    const float4* qs = (const float4*)(q + (size_t)key * ATTN_D + j * 8);
    const float4* ks = (const float4*)(k + (size_t)key * ATTN_D + j * 8);
    float4 a0 = qs[0], a1 = qs[1];
    float4 b0 = ks[0], b1 = ks[1];
    bf16x8 qo, ko;
    qo[0] = (bf16_t)(a0.x * sc); qo[1] = (bf16_t)(a0.y * sc);
    qo[2] = (bf16_t)(a0.z * sc); qo[3] = (bf16_t)(a0.w * sc);
    qo[4] = (bf16_t)(a1.x * sc); qo[5] = (bf16_t)(a1.y * sc);
    qo[6] = (bf16_t)(a1.z * sc); qo[7] = (bf16_t)(a1.w * sc);
    ko[0] = (bf16_t)b0.x; ko[1] = (bf16_t)b0.y;
    ko[2] = (bf16_t)b0.z; ko[3] = (bf16_t)b0.w;
    ko[4] = (bf16_t)b1.x; ko[5] = (bf16_t)b1.y;
    ko[6] = (bf16_t)b1.z; ko[7] = (bf16_t)b1.w;
    *(bf16x8*)(qb + (size_t)key * ATTN_D + j * 8) = qo;
    *(bf16x8*)(kswz + (size_t)key * ATTN_D + ((j ^ (key & 15)) * 8)) = ko;
  }

  {
    const float* src = v + (size_t)key * ATTN_D + bd * 64 + (t & 3) * 16;
#pragma unroll
    for (int u = 0; u < 4; ++u) {
      float4 a = ((const float4*)src)[u];
      tile[row_l][(t & 3) * 16 + u * 4 + 0] = (bf16_t)a.x;
      tile[row_l][(t & 3) * 16 + u * 4 + 1] = (bf16_t)a.y;
      tile[row_l][(t & 3) * 16 + u * 4 + 2] = (bf16_t)a.z;
      tile[row_l][(t & 3) * 16 + u * 4 + 3] = (bf16_t)a.w;
    }
  }
  __syncthreads();
  {
    const int d_l = t >> 2;            // 0..63
    const int d = bd * 64 + d_l;
    const int cq = t & 3;              // chunk 0..3
#pragma unroll
    for (int h = 0; h < 2; ++h) {      // two 32-key v-tiles in this block
      bf16x8 o;
#pragma unroll
      for (int j = 0; j < 8; ++j) {
        const int kl_ = h * 32 + cq * 4 + (j >> 1) + 16 * (j & 1);
        o[j] = tile[kl_][d_l];
      }
      *(bf16x8*)(vtswz + (size_t)(2 * bk + h) * TILE_ELEMS + d * TKEYS +
                 ((cq ^ ((d >> 1) & 3)) * 8)) = o;
    }
  }
}

// ---------------------------------------------------------------------------
// Flash attention, 128 queries/block x 8-way split-K, counted-vmcnt pipeline.
//   grid = 512 blocks x 512 threads (8 waves), LDS 74 KB -> 2 blocks/CU.
//   Block b: query group b>>3 (rows 128*(b>>3)..+127), key eighth b&7.
//   Wave w owns rows w*16..+15 and the FULL 32-key tile (no key split ->
//   no cross-wave O merge; each wave stores its own 16 output rows).
//   4-deep LDS ring: DMA for tile t+3 issued at top of iter t; end of iter
//   waits s_waitcnt vmcnt(4) (tile t+1 landed, t+2/t+3 still in flight) +
//   raw s_barrier -- NEVER vmcnt(0) in steady state (T4, m218: the drain-0
//   barrier was the ~70% stall in the previous 2-buffer structure).
//   Per wave-iter: 8 QK-MFMA + 8 PV-MFMA, exp2-only softmax, s_setprio(1)
//   around MFMA clusters (T5). Writes UNNORMALIZED partial O + partial L;
//   merge kernel sums the 8 split-K partials and normalizes.
//   XCD residency: blockIdx%8 = XCD = b&7 = key eighth, so each XCD's L2
//   holds one 512 KB K/V eighth; co-resident blocks (b, b+256) share the
//   eighth AND the tile stagger -> constructive L2 sharing.
// MFMA layouts (mfma_f32_16x16x32_bf16, verified gfx950):
//   A: m = lane&15, k = (lane>>4)*8 + j
//   B: n = lane&15, k = (lane>>4)*8 + j
//   C/D: col = lane&15, row = (lane>>4)*4 + reg
// ---------------------------------------------------------------------------
__global__ __launch_bounds__(512, 4) void flash_attn_kernel(
    const bf16_t* __restrict__ qb, const bf16_t* __restrict__ kswz,
    const bf16_t* __restrict__ vtswz, float* __restrict__ partO,
    float* __restrict__ partL) {
  __shared__ __align__(16) bf16_t KV[NBUF][2][TILE_ELEMS];  // 64 KB ring
  __shared__ __align__(16) bf16_t Ps[8][16][40];            // 10 KB

  const int t = threadIdx.x;
  const int w = t >> 6;          // 0..7 = row subtile
  const int lane = t & 63;
  const int quad = lane >> 4;
  const int col = lane & 15;
  const int blk = blockIdx.x;
  const int qg = blk >> 3;       // 0..63
  const int kh = blk & 7;        // key eighth == XCD
  const int q0 = qg * QROWS;
  const int ktbase = kh * KTPB;
  const int stg = ((blk >> 3) & 3) * 8;   // stagger: decorrelate L2 streams

  // Swizzled LDS offsets (row*stride + (chunk^swz)*8).
  int offK[4][2], offV[8];
#pragma unroll
  for (int c = 0; c < 4; ++c)
#pragma unroll
    for (int ni = 0; ni < 2; ++ni)
      offK[c][ni] = (ni * 16 + col) * ATTN_D + (((c * 4 + quad) ^ col) * 8);
#pragma unroll
  for (int ds = 0; ds < 8; ++ds)
    offV[ds] = (ds * 16 + col) * TKEYS + ((quad ^ ((col >> 1) & 3)) * 8);

  // Q fragments: one 16-row subtile x 4 k-chunks, registers for whole kernel.
  bf16x8 aq[4];
  {
    const int row = q0 + w * 16 + col;
#pragma unroll
    for (int c = 0; c < 4; ++c)
      aq[c] = *(const bf16x8*)(qb + (size_t)row * ATTN_D + c * 32 + quad * 8);
  }

  f32x4 oacc[8];
#pragma unroll
  for (int i = 0; i < 8; ++i) oacc[i] = (f32x4){0.f, 0.f, 0.f, 0.f};
  float l_part[4] = {0.f, 0.f, 0.f, 0.f};

  // Prologue: tiles 0..2 into bufs 0..2 (1 K-dma + 1 V-dma per thread each).
#pragma unroll
  for (int pt = 0; pt < 3; ++pt) {
    const int kt = ktbase + ((stg + pt) & (KTPB - 1));
    dma16(kswz + (size_t)kt * TILE_ELEMS + t * 8, &KV[pt][0][t * 8]);
    dma16(vtswz + (size_t)kt * TILE_ELEMS + t * 8, &KV[pt][1][t * 8]);
  }
  asm volatile("s_waitcnt vmcnt(4)" ::: "memory");  // tile 0 landed; 1,2 fly
  __builtin_amdgcn_s_barrier();

  for (int it = 0; it < KTPB; ++it) {
    const int buf = it & (NBUF - 1);
    if (it + 3 < KTPB) {
      const int nt = ktbase + ((stg + it + 3) & (KTPB - 1));
      const int nb = (it + 3) & (NBUF - 1);
      dma16(kswz + (size_t)nt * TILE_ELEMS + t * 8, &KV[nb][0][t * 8]);
      dma16(vtswz + (size_t)nt * TILE_ELEMS + t * 8, &KV[nb][1][t * 8]);
    }
    const bf16_t* Kb = KV[buf][0];
    const bf16_t* Vb = KV[buf][1];

    // --- S = Q K^T over the 32-key tile (2 n-subtiles).
    f32x4 s0 = (f32x4){0.f, 0.f, 0.f, 0.f};
    f32x4 s1 = (f32x4){0.f, 0.f, 0.f, 0.f};
    __builtin_amdgcn_s_setprio(1);
#pragma unroll
    for (int c = 0; c < 4; ++c) {
      bf16x8 b0 = *(const bf16x8*)(Kb + offK[c][0]);
      bf16x8 b1 = *(const bf16x8*)(Kb + offK[c][1]);
      s0 = __builtin_amdgcn_mfma_f32_16x16x32_bf16(aq[c], b0, s0, 0, 0, 0);
      s1 = __builtin_amdgcn_mfma_f32_16x16x32_bf16(aq[c], b1, s1, 0, 0, 0);
    }
    __builtin_amdgcn_s_setprio(0);

    // --- p = 2^s; lane-local denominator; packed pair-store (key i <-> pos
    //     2i, key i+16 <-> pos 2i+1).
#pragma unroll
    for (int r = 0; r < 4; ++r) {
      float p0 = EXP2(s0[r]);
      float p1 = EXP2(s1[r]);
      l_part[r] += p0 + p1;
      *(bf16x2*)&Ps[w][quad * 4 + r][col * 2] = (bf16x2){(bf16_t)p0, (bf16_t)p1};
    }

    // --- O += P V (K-dim = the 32 keys, permuted order matches V image).
    bf16x8 ap = *(const bf16x8*)&Ps[w][col][quad * 8];
    __builtin_amdgcn_s_setprio(1);
#pragma unroll
    for (int ds = 0; ds < 8; ++ds) {
      bf16x8 bv = *(const bf16x8*)(Vb + offV[ds]);
      oacc[ds] = __builtin_amdgcn_mfma_f32_16x16x32_bf16(ap, bv, oacc[ds], 0, 0, 0);
    }
    __builtin_amdgcn_s_setprio(0);

    // --- counted wait: tile it+1 must have landed; newer tiles stay in
    //     flight across the barrier (T4). Tail iters drain what's left.
    if (it + 3 < KTPB) {
      asm volatile("s_waitcnt vmcnt(4)" ::: "memory");
      __builtin_amdgcn_s_barrier();
    } else if (it + 2 < KTPB) {
      asm volatile("s_waitcnt vmcnt(2)" ::: "memory");
      __builtin_amdgcn_s_barrier();
    } else if (it + 1 < KTPB) {
      asm volatile("s_waitcnt vmcnt(0)" ::: "memory");
      __builtin_amdgcn_s_barrier();
    }
  }

  // --- epilogue: partial L (reduce over the 16 col-lanes of each quad).
#pragma unroll
  for (int r = 0; r < 4; ++r) {
    float v = l_part[r];
#pragma unroll
    for (int off = 1; off < 16; off <<= 1)
      v += __shfl_xor(v, off, 64);
    if (col == 0)
      partL[(size_t)blk * QROWS + w * 16 + quad * 4 + r] = v;
  }

  // --- direct store of this wave's 16 unnormalized O rows (no LDS merge).
  {
    float* dst = partO + ((size_t)blk * QROWS + w * 16) * ATTN_D;
#pragma unroll
    for (int ds = 0; ds < 8; ++ds)
#pragma unroll
      for (int r = 0; r < 4; ++r)
        dst[(quad * 4 + r) * ATTN_D + ds * 16 + col] = oacc[ds][r];
  }
}

// ---------------------------------------------------------------------------
// Merge: out[row] = (sum of 8 split-K partial O) / (sum of 8 partial L).
//   1024 blocks x 256 threads, one float4 per thread.
// ---------------------------------------------------------------------------
__global__ void merge_kernel(const float* __restrict__ partO,
                             const float* __restrict__ partL,
                             float* __restrict__ out) {
  const int idx = blockIdx.x * blockDim.x + threadIdx.x;  // float4 index
  const int row = idx >> 5;          // 32 float4 per 128-elem row
  const int gi = row >> 7;           // query group 0..63
  const int rl = row & 127;
  const int li = rl * 32 + (idx & 31);
  float L = 0.f;
  float4 acc = {0.f, 0.f, 0.f, 0.f};
#pragma unroll
  for (int i = 0; i < 8; ++i) {
    const size_t b = (size_t)(8 * gi + i);
    L += partL[b * QROWS + rl];
    float4 a = ((const float4*)(partO + b * (QROWS * ATTN_D)))[li];
    acc.x += a.x; acc.y += a.y; acc.z += a.z; acc.w += a.w;
  }
  const float invL = 1.0f / L;
  float4 o;
  o.x = acc.x * invL; o.y = acc.y * invL;
  o.z = acc.z * invL; o.w = acc.w * invL;
  ((float4*)out)[idx] = o;
}

// ---------------------------------------------------------------------------
extern "C" void kernel_launch(void* const* d_in, const int* in_sizes, int n_in,
                              void* d_out, int out_size, void* d_ws, size_t ws_size,
                              hipStream_t stream) {
  const float* q = (const float*)d_in[0];
  const float* k = (const float*)d_in[1];
  const float* v = (const float*)d_in[2];
  float* out = (float*)d_out;

  // Workspace: qb | kswz | vtswz (bf16, 2 MB each) | partO 33.6 MB | partL 256 KB.
  bf16_t* qb = (bf16_t*)d_ws;
  bf16_t* kswz = qb + (size_t)ATTN_N * ATTN_D;
  bf16_t* vtswz = kswz + (size_t)ATTN_N * ATTN_D;
  float* partO = (float*)(vtswz + (size_t)ATTN_N * ATTN_D);
  float* partL = partO + (size_t)512 * QROWS * ATTN_D;

  prep_kernel<<<dim3(ATTN_N / 64, 2), 256, 0, stream>>>(q, k, v, qb, kswz, vtswz);
  flash_attn_kernel<<<512, 512, 0, stream>>>(qb, kswz, vtswz, partO, partL);
  merge_kernel<<<(ATTN_N * ATTN_D / 4) / 256, 256, 0, stream>>>(partO, partL, out);
}